// Round 1
// baseline (365.703 us; speedup 1.0000x reference)
//
#include <hip/hip_runtime.h>
#include <cmath>
#include <cstdint>

// logm(SPD) via Chebyshev polynomial of T=(A-mI)/h on spectrum [0.98,5.8].
// One 128x128 matrix per workgroup, fully LDS-resident Horner iteration:
//   P <- P*T + a_k I,  P carried as bf16 hi+lo split, MFMA 16x16x32 bf16.
// All intermediates are symmetric => store transposed, both operand frags are
// contiguous row reads; XOR-swizzle (row&7)<<4 kills 256B-stride conflicts.

#define DEG 10

using f32x4 = __attribute__((ext_vector_type(4))) float;
using s16x8 = __attribute__((ext_vector_type(8))) short;

struct Coeffs { float a[DEG + 1]; float mc; float hinv; };

__device__ __forceinline__ uint32_t bf16rn(float f) {
  uint32_t u = __builtin_bit_cast(uint32_t, f);
  return (u + 0x7fffu + ((u >> 16) & 1u)) >> 16;  // round-to-nearest-even
}
__device__ __forceinline__ float bf16tof(uint32_t h) {
  return __builtin_bit_cast(float, h << 16);
}
__device__ __forceinline__ uint32_t swzoff(uint32_t row, uint32_t byteInRow) {
  // 256B rows; XOR bits 4-6 with row&7 -> conflict-free b128/b64 access
  return (row << 8) + (byteInRow ^ ((row & 7u) << 4));
}

__global__ __launch_bounds__(512, 2) void logm_poly(
    const float* __restrict__ A, float* __restrict__ Out, Coeffs cf) {
  extern __shared__ char smem[];
  char* Tb = smem;                 // 32KB bf16 T
  char* Ph = smem + 32 * 1024;     // 32KB bf16 P hi
  char* Pl = smem + 64 * 1024;     // 32KB bf16 P lo

  const int tid  = threadIdx.x;
  const int lane = tid & 63;
  const int wid  = tid >> 6;   // 0..7
  const int wr   = wid >> 1;   // 0..3 : rows 32*wr..+31
  const int wc   = wid & 1;    // 0..1 : cols 64*wc..+63
  const int q    = lane >> 4;  // quarter
  const int lr   = lane & 15;

  const size_t mbase = (size_t)blockIdx.x * 16384;
  const float* Ag = A + mbase;
  float* Og = Out + mbase;

  // ---- stage: load A (fp32), build T = (A - m I)/h, init P = a[D]*T + a[D-1]*I
  #pragma unroll
  for (int i = 0; i < 8; ++i) {
    int f = tid + 512 * i;          // float4 index
    int r = f >> 5;                 // row
    int c = (f & 31) << 2;          // col (multiple of 4)
    f32x4 v = *(const f32x4*)(Ag + r * 128 + c);
    uint32_t th[4], hh[4], ll[4];
    #pragma unroll
    for (int j = 0; j < 4; ++j) {
      float diag = (r == c + j) ? 1.f : 0.f;
      float t = (v[j] - cf.mc * diag) * cf.hinv;
      float p = cf.a[DEG] * t + cf.a[DEG - 1] * diag;
      th[j] = bf16rn(t);
      hh[j] = bf16rn(p);
      ll[j] = bf16rn(p - bf16tof(hh[j]));
    }
    uint32_t off = swzoff((uint32_t)r, (uint32_t)(c * 2));
    *(uint2*)(Tb + off) = make_uint2(th[0] | (th[1] << 16), th[2] | (th[3] << 16));
    *(uint2*)(Ph + off) = make_uint2(hh[0] | (hh[1] << 16), hh[2] | (hh[3] << 16));
    *(uint2*)(Pl + off) = make_uint2(ll[0] | (ll[1] << 16), ll[2] | (ll[3] << 16));
  }
  __syncthreads();

  // ---- preload T fragments for this wave's 4 col-blocks (kept all steps)
  s16x8 tf[4][4];
  #pragma unroll
  for (int cb = 0; cb < 4; ++cb)
    #pragma unroll
    for (int kc = 0; kc < 4; ++kc) {
      int s = 64 * wc + 16 * cb + lr;       // T col == T row (symmetric)
      tf[cb][kc] = *(const s16x8*)(Tb + swzoff((uint32_t)s, (uint32_t)(kc * 64 + q * 16)));
    }

  // ---- Horner: 9 steps, P <- P*T + a[k] I
  #pragma unroll
  for (int k = DEG - 2; k >= 0; --k) {
    s16x8 pfh[2][4], pfl[2][4];
    #pragma unroll
    for (int rb = 0; rb < 2; ++rb)
      #pragma unroll
      for (int kc = 0; kc < 4; ++kc) {
        int r = 32 * wr + 16 * rb + lr;
        uint32_t off = swzoff((uint32_t)r, (uint32_t)(kc * 64 + q * 16));
        pfh[rb][kc] = *(const s16x8*)(Ph + off);
        pfl[rb][kc] = *(const s16x8*)(Pl + off);
      }
    __syncthreads();  // all reads of P done before anyone overwrites

    f32x4 acc[2][4];
    #pragma unroll
    for (int rb = 0; rb < 2; ++rb)
      #pragma unroll
      for (int cb = 0; cb < 4; ++cb) {
        f32x4 a = {0.f, 0.f, 0.f, 0.f};
        #pragma unroll
        for (int kc = 0; kc < 4; ++kc) {
          a = __builtin_amdgcn_mfma_f32_16x16x32_bf16(pfl[rb][kc], tf[cb][kc], a, 0, 0, 0);
          a = __builtin_amdgcn_mfma_f32_16x16x32_bf16(pfh[rb][kc], tf[cb][kc], a, 0, 0, 0);
        }
        if (2 * wr + rb == 4 * wc + cb) {     // tile on the block diagonal
          int reg = lr - q * 4;
          if (reg >= 0 && reg < 4) a[reg] += cf.a[k];
        }
        acc[rb][cb] = a;
      }

    if (k > 0) {
      // write P' (transposed = same matrix) as bf16 hi+lo, one b64 each
      #pragma unroll
      for (int rb = 0; rb < 2; ++rb)
        #pragma unroll
        for (int cb = 0; cb < 4; ++cb) {
          int s    = 64 * wc + 16 * cb + lr;        // storage row = out col
          int rowb = 32 * wr + 16 * rb + q * 4;     // 4 consecutive out rows
          uint32_t off = swzoff((uint32_t)s, (uint32_t)(rowb * 2));
          uint32_t h0 = bf16rn(acc[rb][cb][0]), h1 = bf16rn(acc[rb][cb][1]);
          uint32_t h2 = bf16rn(acc[rb][cb][2]), h3 = bf16rn(acc[rb][cb][3]);
          uint32_t l0 = bf16rn(acc[rb][cb][0] - bf16tof(h0));
          uint32_t l1 = bf16rn(acc[rb][cb][1] - bf16tof(h1));
          uint32_t l2 = bf16rn(acc[rb][cb][2] - bf16tof(h2));
          uint32_t l3 = bf16rn(acc[rb][cb][3] - bf16tof(h3));
          *(uint2*)(Ph + off) = make_uint2(h0 | (h1 << 16), h2 | (h3 << 16));
          *(uint2*)(Pl + off) = make_uint2(l0 | (l1 << 16), l2 | (l3 << 16));
        }
      __syncthreads();
    } else {
      // final: write fp32 result to global
      #pragma unroll
      for (int rb = 0; rb < 2; ++rb)
        #pragma unroll
        for (int cb = 0; cb < 4; ++cb) {
          int colo = 64 * wc + 16 * cb + lr;
          int rowb = 32 * wr + 16 * rb + q * 4;
          #pragma unroll
          for (int reg = 0; reg < 4; ++reg)
            Og[(size_t)(rowb + reg) * 128 + colo] = acc[rb][cb][reg];
        }
    }
  }
}

extern "C" void kernel_launch(void* const* d_in, const int* in_sizes, int n_in,
                              void* d_out, int out_size, void* d_ws, size_t ws_size,
                              hipStream_t stream) {
  const float* A = (const float*)d_in[0];
  float* Out = (float*)d_out;
  int nmat = in_sizes[0] / 16384;

  // Chebyshev coefficients of log on [lo,hi], closed form via generating fn:
  // log(m+h t) = log m - log(1+q^2) - 2 sum_{n>=1} (q^n/n) T_n(t),
  // q = (sqrt(1-a^2)-1)/a, a = h/m.  Then convert to monomial basis (double).
  const double lo = 0.98, hi = 5.80;
  double m = 0.5 * (lo + hi), h = 0.5 * (hi - lo);
  double al = h / m;
  double sq = std::sqrt(1.0 - al * al);
  double qv = (sq - 1.0) / al;
  double c[DEG + 1];
  c[0] = std::log(m) - std::log1p(qv * qv);
  double qp = 1.0;
  for (int n = 1; n <= DEG; ++n) { qp *= qv; c[n] = -2.0 * qp / n; }

  double mono[DEG + 1], Tm1[DEG + 1], T0[DEG + 1], Tn[DEG + 1];
  for (int i = 0; i <= DEG; ++i) { mono[i] = 0; Tm1[i] = 0; T0[i] = 0; Tn[i] = 0; }
  Tm1[0] = 1; mono[0] += c[0];
  T0[1] = 1;  mono[1] += c[1];
  for (int n = 2; n <= DEG; ++n) {
    for (int i = 0; i <= DEG; ++i)
      Tn[i] = (i > 0 ? 2.0 * T0[i - 1] : 0.0) - Tm1[i];
    for (int i = 0; i <= DEG; ++i) {
      mono[i] += c[n] * Tn[i];
      Tm1[i] = T0[i];
      T0[i] = Tn[i];
    }
  }

  Coeffs cf;
  for (int i = 0; i <= DEG; ++i) cf.a[i] = (float)mono[i];
  cf.mc = (float)m;
  cf.hinv = (float)(1.0 / h);

  (void)hipFuncSetAttribute((const void*)logm_poly,
                            hipFuncAttributeMaxDynamicSharedMemorySize, 96 * 1024);
  logm_poly<<<dim3(nmat), dim3(512), 96 * 1024, stream>>>(A, Out, cf);
}

// Round 2
// 284.867 us; speedup vs baseline: 1.2838x; 1.2838x over previous
//
#include <hip/hip_runtime.h>
#include <cmath>
#include <cstdint>

// logm(SPD) via degree-7 Chebyshev polynomial of T=(A-mI)/h on [0.98,5.8].
// One 128x128 matrix per 1024-thread workgroup (16 waves, 16x64 tile each),
// LDS-resident Horner: P <- P*T + a_k I, P as bf16 hi+lo (trunc split),
// ping-pong buffers (1 barrier/step), XOR-swizzled LDS rows.

#define DEG 7
#define NSTEP (DEG - 1)  // 6

using f32x4 = __attribute__((ext_vector_type(4))) float;
using s16x8 = __attribute__((ext_vector_type(8))) short;

struct Coeffs { float a[DEG + 1]; float mc; float hinv; };

__device__ __forceinline__ uint32_t swzoff(uint32_t row, uint32_t byteInRow) {
  // 256B rows; XOR bits 4-6 with row&7 -> spreads 16B slots across banks
  return (row << 8) + (byteInRow ^ ((row & 7u) << 4));
}

__global__ __launch_bounds__(1024) void logm_poly(
    const float* __restrict__ A, float* __restrict__ Out, Coeffs cf) {
  extern __shared__ char smem[];
  char* Ah = smem;                  // P hi, buffer A
  char* Al = smem + 32 * 1024;      // P lo, buffer A
  char* Bh = smem + 64 * 1024;      // P hi, buffer B (T staged here first)
  char* Bl = smem + 96 * 1024;      // P lo, buffer B

  const int tid  = threadIdx.x;
  const int lane = tid & 63;
  const int wid  = tid >> 6;   // 0..15
  const int wr   = wid >> 1;   // 0..7 : rows 16*wr..+15
  const int wc   = wid & 1;    // 0..1 : cols 64*wc..+63
  const int q    = lane >> 4;
  const int lr   = lane & 15;

  const size_t mbase = (size_t)blockIdx.x * 16384;
  const float* Ag = A + mbase;
  float* Og = Out + mbase;

  // ---- stage: T (RNE bf16) -> Bh; P = a[DEG]*T + a[DEG-1]*I -> Ah/Al
  #pragma unroll
  for (int i = 0; i < 4; ++i) {
    int f = tid + 1024 * i;        // float4 index
    int r = f >> 5;
    int c = (f & 31) << 2;
    f32x4 v = *(const f32x4*)(Ag + r * 128 + c);
    uint32_t tb[4], hb[4], lb[4];
    #pragma unroll
    for (int j = 0; j < 4; ++j) {
      float diag = (r == c + j) ? 1.f : 0.f;
      float t = (v[j] - cf.mc * diag) * cf.hinv;
      uint32_t ub = __builtin_bit_cast(uint32_t, t);
      tb[j] = (ub + 0x7fffu + ((ub >> 16) & 1u)) & 0xffff0000u;  // RNE bf16, high-aligned
      float tr = __builtin_bit_cast(float, tb[j]);
      float p = cf.a[DEG] * tr + cf.a[DEG - 1] * diag;
      hb[j] = __builtin_bit_cast(uint32_t, p) & 0xffff0000u;     // trunc hi
      lb[j] = __builtin_bit_cast(uint32_t, p - __builtin_bit_cast(float, hb[j]));
    }
    uint32_t off = swzoff((uint32_t)r, (uint32_t)(c * 2));
    *(uint2*)(Bh + off) = make_uint2((tb[0] >> 16) | tb[1], (tb[2] >> 16) | tb[3]);
    *(uint2*)(Ah + off) = make_uint2((hb[0] >> 16) | hb[1], (hb[2] >> 16) | hb[3]);
    *(uint2*)(Al + off) = make_uint2((lb[0] >> 16) | (lb[1] & 0xffff0000u),
                                     (lb[2] >> 16) | (lb[3] & 0xffff0000u));
  }
  __syncthreads();

  // ---- preload T fragments (this wave's 4 col-blocks), kept all steps
  s16x8 tf[4][4];
  #pragma unroll
  for (int cb = 0; cb < 4; ++cb) {
    int s = 64 * wc + 16 * cb + lr;   // T col == T row (symmetric)
    #pragma unroll
    for (int kc = 0; kc < 4; ++kc)
      tf[cb][kc] = *(const s16x8*)(Bh + swzoff((uint32_t)s, (uint32_t)(kc * 64 + q * 16)));
  }
  __syncthreads();

  // ---- Horner: 6 steps, P <- P*T + a[k] I, ping-pong A<->B
  #pragma unroll
  for (int i = 0; i < NSTEP; ++i) {
    const int k = DEG - 2 - i;
    const char* Sh = (i & 1) ? Bh : Ah;
    const char* Sl = (i & 1) ? Bl : Al;
    char* Dh = (i & 1) ? Ah : Bh;
    char* Dl = (i & 1) ? Al : Bl;

    s16x8 pfh[4], pfl[4];
    {
      int r = 16 * wr + lr;
      #pragma unroll
      for (int kc = 0; kc < 4; ++kc) {
        uint32_t off = swzoff((uint32_t)r, (uint32_t)(kc * 64 + q * 16));
        pfh[kc] = *(const s16x8*)(Sh + off);
        pfl[kc] = *(const s16x8*)(Sl + off);
      }
    }

    #pragma unroll
    for (int cb = 0; cb < 4; ++cb) {
      f32x4 a = {0.f, 0.f, 0.f, 0.f};
      #pragma unroll
      for (int kc = 0; kc < 4; ++kc) {
        a = __builtin_amdgcn_mfma_f32_16x16x32_bf16(pfl[kc], tf[cb][kc], a, 0, 0, 0);
        a = __builtin_amdgcn_mfma_f32_16x16x32_bf16(pfh[kc], tf[cb][kc], a, 0, 0, 0);
      }
      if (wr == 4 * wc + cb) {            // 16x16 tile on the diagonal
        int reg = lr - 4 * q;
        if (reg >= 0 && reg < 4) a[reg] += cf.a[k];
      }

      if (i < NSTEP - 1) {
        // write P' transposed (= same matrix, symmetric) as trunc hi + lo
        uint32_t h0 = __builtin_bit_cast(uint32_t, a[0]) & 0xffff0000u;
        uint32_t h1 = __builtin_bit_cast(uint32_t, a[1]) & 0xffff0000u;
        uint32_t h2 = __builtin_bit_cast(uint32_t, a[2]) & 0xffff0000u;
        uint32_t h3 = __builtin_bit_cast(uint32_t, a[3]) & 0xffff0000u;
        uint32_t l0 = __builtin_bit_cast(uint32_t, a[0] - __builtin_bit_cast(float, h0));
        uint32_t l1 = __builtin_bit_cast(uint32_t, a[1] - __builtin_bit_cast(float, h1));
        uint32_t l2 = __builtin_bit_cast(uint32_t, a[2] - __builtin_bit_cast(float, h2));
        uint32_t l3 = __builtin_bit_cast(uint32_t, a[3] - __builtin_bit_cast(float, h3));
        int s = 64 * wc + 16 * cb + lr;            // storage row = out col
        uint32_t off = swzoff((uint32_t)s, (uint32_t)((16 * wr + 4 * q) * 2));
        *(uint2*)(Dh + off) = make_uint2((h0 >> 16) | h1, (h2 >> 16) | h3);
        *(uint2*)(Dl + off) = make_uint2((l0 >> 16) | (l1 & 0xffff0000u),
                                         (l2 >> 16) | (l3 & 0xffff0000u));
      } else {
        int colo = 64 * wc + 16 * cb + lr;
        int rowb = 16 * wr + 4 * q;
        #pragma unroll
        for (int reg = 0; reg < 4; ++reg)
          Og[(size_t)(rowb + reg) * 128 + colo] = a[reg];
      }
    }
    if (i < NSTEP - 1) __syncthreads();
  }
}

extern "C" void kernel_launch(void* const* d_in, const int* in_sizes, int n_in,
                              void* d_out, int out_size, void* d_ws, size_t ws_size,
                              hipStream_t stream) {
  const float* A = (const float*)d_in[0];
  float* Out = (float*)d_out;
  int nmat = in_sizes[0] / 16384;

  // Chebyshev coeffs of log on [lo,hi] (closed form), then monomial basis.
  const double lo = 0.98, hi = 5.80;
  double m = 0.5 * (lo + hi), h = 0.5 * (hi - lo);
  double al = h / m;
  double sq = std::sqrt(1.0 - al * al);
  double qv = (sq - 1.0) / al;
  double c[DEG + 1];
  c[0] = std::log(m) - std::log1p(qv * qv);
  double qp = 1.0;
  for (int n = 1; n <= DEG; ++n) { qp *= qv; c[n] = -2.0 * qp / n; }

  double mono[DEG + 1], Tm1[DEG + 1], T0[DEG + 1], Tn[DEG + 1];
  for (int i = 0; i <= DEG; ++i) { mono[i] = 0; Tm1[i] = 0; T0[i] = 0; Tn[i] = 0; }
  Tm1[0] = 1; mono[0] += c[0];
  T0[1] = 1;  mono[1] += c[1];
  for (int n = 2; n <= DEG; ++n) {
    for (int i = 0; i <= DEG; ++i)
      Tn[i] = (i > 0 ? 2.0 * T0[i - 1] : 0.0) - Tm1[i];
    for (int i = 0; i <= DEG; ++i) {
      mono[i] += c[n] * Tn[i];
      Tm1[i] = T0[i];
      T0[i] = Tn[i];
    }
  }

  Coeffs cf;
  for (int i = 0; i <= DEG; ++i) cf.a[i] = (float)mono[i];
  cf.mc = (float)m;
  cf.hinv = (float)(1.0 / h);

  (void)hipFuncSetAttribute((const void*)logm_poly,
                            hipFuncAttributeMaxDynamicSharedMemorySize, 128 * 1024);
  logm_poly<<<dim3(nmat), dim3(1024), 128 * 1024, stream>>>(A, Out, cf);
}